// Round 10
// baseline (144.885 us; speedup 1.0000x reference)
//
#include <hip/hip_runtime.h>
#include <hip/hip_bf16.h>

// MHA block: B=2, S=2048, D_MODEL=512, H=8, D_K=64.
// convert (weights+biases+dtype flag ONLY, ~6 MB) -> fused QKV GEMM (128x128
// tiles; A staged REG->LDS with inline f32->bf16 convert from RAW inputs --
// the 48MB activation conversion pass is deleted; W via global_load_lds from
// converted weights; ONE __syncthreads per K-step; Q pre-scaled 0.125*log2e;
// V transposed [bh][d][s]) -> flash attention (r9 verified: 512 blocks x 512
// threads, 8 waves = (q-half)x(key-quarter), 128 keys/iter, one sync/iter,
// swapped QK^T identity-slotted, in-register P, fixed-max exp2 softmax,
// O^T = mfma(Vt,P), LDS merge) -> output GEMM (64x64, dtype flag).

typedef __attribute__((ext_vector_type(8))) short short8;   // 8 bf16 (4 VGPRs)
typedef __attribute__((ext_vector_type(4))) short short4v;  // 4 bf16 (8B)
typedef __attribute__((ext_vector_type(4))) float f32x4;    // MFMA 16x16 accum
typedef __attribute__((ext_vector_type(4))) unsigned int uint4v;

#define DM 512
#define SEQ 2048
#define NROW 4096   // B * SEQ
#define LOG2E 1.44269504088896341f
#define MFMA(a, b, c) __builtin_amdgcn_mfma_f32_16x16x32_bf16(a, b, c, 0, 0, 0)
#define FENCE() __asm__ __volatile__("" ::: "memory")

#if __has_builtin(__builtin_amdgcn_exp2f)
#define EXP2(x) __builtin_amdgcn_exp2f(x)
#else
#define EXP2(x) exp2f(x)
#endif

__device__ __forceinline__ float bf_bits2f(short s) {
    unsigned int u = ((unsigned int)(unsigned short)s) << 16;
    return __builtin_bit_cast(float, u);
}
__device__ __forceinline__ short f2bf_r(float f) {   // round-half-up, 2 VALU
    unsigned int u = __builtin_bit_cast(unsigned int, f) + 0x8000u;
    return (short)(u >> 16);
}
__device__ __forceinline__ unsigned int pack_bf16(float lo, float hi) {
    unsigned int ul = __builtin_bit_cast(unsigned int, lo) + 0x8000u;
    unsigned int uh = __builtin_bit_cast(unsigned int, hi) + 0x8000u;
    return __builtin_amdgcn_perm(uh, ul, 0x07060302u);
}

__device__ __forceinline__ void gload_lds16(const void* src, void* lds_dst) {
    __builtin_amdgcn_global_load_lds(
        (const __attribute__((address_space(1))) unsigned int*)src,
        (__attribute__((address_space(3))) unsigned int*)lds_dst, 16, 0, 0);
}

// Stage ROWSx64 bf16 tile into LDS; granule swizzle swz(row) = (row>>SH)&7:
// LDS[row][b] = global[row][b ^ swz(row)] (16B blocks). Read accessor for
// global [row][cb*8+j]: lds[row*64 + ((cb ^ swz(row))*8) + j].
template <int ROWS, int NW, int SH = 0>
__device__ __forceinline__ void stage_tile(const short* __restrict__ gsrc, size_t gstride,
                                           short* lds, int wave, int lane) {
    constexpr int ISSUES = ROWS * 8 / (64 * NW);
    #pragma unroll
    for (int i = 0; i < ISSUES; i++) {
        const int blk = i * NW + wave;
        const int g = blk * 64 + lane;
        const int row = g >> 3;
        const int cb = (g & 7) ^ ((row >> SH) & 7);
        gload_lds16(gsrc + (size_t)row * gstride + cb * 8, lds + (size_t)blk * 512);
    }
}

// Dtype vote over first 1024 words of q. true = f32 inputs.
__device__ __forceinline__ bool detect_f32(const unsigned int* __restrict__ q, int* cnt_lds) {
    if (threadIdx.x == 0) *cnt_lds = 0;
    __syncthreads();
    int local = 0;
    for (int i = threadIdx.x; i < 1024; i += blockDim.x) {
        unsigned int lo = q[i] & 0x7FFFu;
        if (lo >= 0x3000u && lo < 0x4400u) local++;
    }
    if (local) atomicAdd(cnt_lds, local);
    __syncthreads();
    return *cnt_lds < 512;
}

// ---------------------------------------------------------------------------
// Convert ONLY weights + biases (8 small tensors, ~6 MB moved) + write flag.
struct ConvArgs { const void* detect_src; const void* src[8]; short* dst[8];
                  int n[8]; int* flag; };
__global__ void convert_all(ConvArgs a) {
    __shared__ int cnt;
    const bool f32m = detect_f32((const unsigned int*)a.detect_src, &cnt);
    if (threadIdx.x == 0) *a.flag = f32m ? 1 : 0;   // all blocks write same value
    const int tid = blockIdx.x * 256 + threadIdx.x;
    const int stride = gridDim.x * 256;
    if (f32m) {
        for (int s = 0; s < 8; s++) {
            const float4* sp = (const float4*)a.src[s];
            short4v* dp = (short4v*)a.dst[s];
            const int n4 = a.n[s] >> 2;
            for (int i = tid; i < n4; i += stride) {
                float4 v = sp[i];
                short4v o;
                o[0] = f2bf_r(v.x); o[1] = f2bf_r(v.y);
                o[2] = f2bf_r(v.z); o[3] = f2bf_r(v.w);
                dp[i] = o;
            }
        }
    } else {
        for (int s = 0; s < 8; s++) {
            const short4v* sp = (const short4v*)a.src[s];
            short4v* dp = (short4v*)a.dst[s];
            const int n4 = a.n[s] >> 2;
            for (int i = tid; i < n4; i += stride) dp[i] = sp[i];
        }
    }
}

// ---------------------------------------------------------------------------
// Fused QKV projection, 128x128 tiles, 4 waves. A is staged REG->LDS with
// inline dtype conversion from the RAW input tensor (f32 or bf16 per flag);
// W staged via global_load_lds from pre-converted bf16 weights. Protocol:
// ONE __syncthreads per K-step --
//   [issue A(i+1) f32 loads -> regs; issue B(i+1) glds -> buf^1]
//   [compute buf(i): ds_read + MFMA]
//   [ds_write A regs -> buf^1 (compiler-inserted vmcnt covers the loads)]
//   [__syncthreads: drains vmcnt+lgkm; both buffers handed over]
// Safe by construction: every cross-wave handoff crosses a full drain.
// z=0: Q scaled by 0.125*log2e. z=1: K. z=2: V transposed.
struct QKVArgs {
    const void* Araw[3];                 // raw q, k, v (dtype per flag)
    const short* W[3]; const short* Bi[3];
    short* Cq; short* Ck; short* Cv;
    const int* flag;
};
__global__ __launch_bounds__(256, 2) void qkv_gemm(QKVArgs args) {
    __shared__ __align__(16) short Alds[2][128 * 64];   // 32 KB
    __shared__ __align__(16) short Blds[2][128 * 64];   // 32 KB
    const int z = blockIdx.z;
    const bool f32m = (*args.flag != 0);
    const int wave = threadIdx.x >> 6, lane = threadIdx.x & 63;
    const int rc = lane & 15, quad = lane >> 4;
    const int m0 = blockIdx.x * 128, n0 = blockIdx.y * 128;
    const short* Bg = args.W[z] + (size_t)n0 * DM;

    // A reg-staging: 4 granules/lane (granule = 8 bf16 = 16B LDS slot).
    // Same swizzled layout as stage_tile<128,4,0>.
    short8 areg[4];
    auto loadA = [&](int kcol) {
        #pragma unroll
        for (int i = 0; i < 4; i++) {
            const int g = (i * 4 + wave) * 64 + lane;
            const int row = g >> 3;
            const int cb = (g & 7) ^ (row & 7);
            const size_t off = (size_t)(m0 + row) * DM + kcol + cb * 8;
            if (f32m) {
                const float* p = (const float*)args.Araw[z] + off;
                const float4 x = *(const float4*)p;
                const float4 y = *(const float4*)(p + 4);
                uint4v w;
                w[0] = pack_bf16(x.x, x.y); w[1] = pack_bf16(x.z, x.w);
                w[2] = pack_bf16(y.x, y.y); w[3] = pack_bf16(y.z, y.w);
                areg[i] = __builtin_bit_cast(short8, w);
            } else {
                areg[i] = *(const short8*)((const short*)args.Araw[z] + off);
            }
        }
    };
    auto writeA = [&](short* Ab) {
        #pragma unroll
        for (int i = 0; i < 4; i++)
            *(short8*)(Ab + (size_t)(i * 4 + wave) * 512 + lane * 8) = areg[i];
    };

    f32x4 acc[2][8] = {};

    // prologue: tile 0
    loadA(0);
    stage_tile<128, 4>(Bg, DM, &Blds[0][0], wave, lane);
    writeA(&Alds[0][0]);
    __syncthreads();

    for (int i = 0; i < 8; i++) {
        const int cur = i & 1;
        if (i + 1 < 8) {
            loadA((i + 1) * 64);                                   // in flight under compute
            stage_tile<128, 4>(Bg + (i + 1) * 64, DM, &Blds[cur ^ 1][0], wave, lane);
        }
        const short* Ac = &Alds[cur][0];
        const short* Bc = &Blds[cur][0];
        #pragma unroll
        for (int h = 0; h < 2; h++) {
            short8 bf[8];
            #pragma unroll
            for (int nt = 0; nt < 8; nt++) {
                const int br = nt * 16 + rc;
                bf[nt] = *(const short8*)&Bc[br * 64 + (((quad + 4 * h) ^ (br & 7)) * 8)];
            }
            #pragma unroll
            for (int ms = 0; ms < 2; ms++) {
                const int ar = wave * 32 + ms * 16 + rc;
                short8 af = *(const short8*)&Ac[ar * 64 + (((quad + 4 * h) ^ (ar & 7)) * 8)];
                #pragma unroll
                for (int nt = 0; nt < 8; nt++)
                    acc[ms][nt] = MFMA(af, bf[nt], acc[ms][nt]);
            }
        }
        if (i + 1 < 8) writeA(&Alds[cur ^ 1][0]);
        __syncthreads();   // drains A-loads/writes + B glds; releases buf[cur]
    }

    const short* bias = args.Bi[z];
    if (z == 2) {
        #pragma unroll
        for (int ms = 0; ms < 2; ms++) {
            const int mw = m0 + wave * 32 + ms * 16;
            const int b = mw >> 11, sb = (mw & 2047) + quad * 4;
            #pragma unroll
            for (int nt = 0; nt < 8; nt++) {
                const int dg = n0 + nt * 16 + rc;       // global output col = head dim
                const int hh = dg >> 6, dd = dg & 63;
                const float bv = bf_bits2f(bias[dg]);
                short4v pk;
                #pragma unroll
                for (int r = 0; r < 4; r++) pk[r] = f2bf_r(acc[ms][nt][r] + bv);
                *(short4v*)(args.Cv + ((size_t)((b * 8 + hh) * 64 + dd)) * SEQ + sb) = pk;
            }
        }
    } else {
        short* C = (z == 0) ? args.Cq : args.Ck;
        const float sc = (z == 0) ? (0.125f * LOG2E) : 1.0f;
        #pragma unroll
        for (int ms = 0; ms < 2; ms++) {
            const int mw = m0 + wave * 32 + ms * 16;
            #pragma unroll
            for (int nt = 0; nt < 8; nt++) {
                const int col = n0 + nt * 16 + rc;
                const float bv = bf_bits2f(bias[col]);
                #pragma unroll
                for (int r = 0; r < 4; r++)
                    C[(size_t)(mw + quad * 4 + r) * DM + col] = f2bf_r((acc[ms][nt][r] + bv) * sc);
            }
        }
    }
}

// ---------------------------------------------------------------------------
// Output projection: 64x64 tiles, counted-vmcnt double-buffered core
// (verified protocol, unchanged from r9). A = Xp (internal bf16), W = wo.
__global__ __launch_bounds__(256, 4) void out_gemm(
    const short* __restrict__ A, const short* __restrict__ W,
    const short* __restrict__ bias, void* __restrict__ Cout,
    const int* __restrict__ dtf) {
    __shared__ __align__(16) short Alds[2][64 * 64];
    __shared__ __align__(16) short Blds[2][64 * 64];
    const bool f32out = (*dtf != 0);
    const int wave = threadIdx.x >> 6, lane = threadIdx.x & 63;
    const int rc = lane & 15, quad = lane >> 4;
    const int m0 = blockIdx.x * 64, n0 = blockIdx.y * 64;
    const short* Ag = A + (size_t)m0 * DM;
    const short* Bg = W + (size_t)n0 * DM;
    f32x4 acc[4] = {};

    stage_tile<64, 4>(Ag, DM, &Alds[0][0], wave, lane);
    stage_tile<64, 4>(Bg, DM, &Blds[0][0], wave, lane);
    for (int i = 0; i < 8; i++) {
        const int cur = i & 1;
        const short* Ac = &Alds[cur][0];
        const short* Bc = &Blds[cur][0];
        if (i + 1 < 8) {
            stage_tile<64, 4>(Ag + (i + 1) * 64, DM, &Alds[cur ^ 1][0], wave, lane);
            stage_tile<64, 4>(Bg + (i + 1) * 64, DM, &Blds[cur ^ 1][0], wave, lane);
            __builtin_amdgcn_s_waitcnt(0x3F70 | 4);   // vmcnt(4): cur's loads done
        } else {
            __builtin_amdgcn_s_waitcnt(0x3F70);       // vmcnt(0)
        }
        FENCE();
        __builtin_amdgcn_s_barrier();
        FENCE();
        #pragma unroll
        for (int h = 0; h < 2; h++) {
            short8 bf[4];
            #pragma unroll
            for (int nt = 0; nt < 4; nt++) {
                const int br = nt * 16 + rc;
                bf[nt] = *(const short8*)&Bc[br * 64 + (((quad + 4 * h) ^ (br & 7)) * 8)];
            }
            const int ar = wave * 16 + rc;
            short8 af = *(const short8*)&Ac[ar * 64 + (((quad + 4 * h) ^ (ar & 7)) * 8)];
            #pragma unroll
            for (int nt = 0; nt < 4; nt++)
                acc[nt] = MFMA(af, bf[nt], acc[nt]);
        }
        FENCE();
        __builtin_amdgcn_s_barrier();
        FENCE();
    }
    const int mw = m0 + wave * 16;
    #pragma unroll
    for (int nt = 0; nt < 4; nt++) {
        const int col = n0 + nt * 16 + rc;
        const float bv = bf_bits2f(bias[col]);
        #pragma unroll
        for (int r = 0; r < 4; r++) {
            const size_t idx = (size_t)(mw + quad * 4 + r) * DM + col;
            const float val = acc[nt][r] + bv;
            if (f32out) ((float*)Cout)[idx] = val;
            else        ((short*)Cout)[idx] = f2bf_r(val);
        }
    }
}

// ---------------------------------------------------------------------------
// Flash attention (r9, byte-identical; best-known-good): 512 blocks x 512
// threads, 8 waves: qh = wave&1 (32q, ms=2), kh = wave>>1 (key-quarter).
// 16 iters x 128 keys, double-buffered, ONE full-drain __syncthreads/iter.
// Swapped QK^T identity-slotted; in-register P; fixed-max exp2 softmax;
// O^T = mfma(Vt,P); 4 key-quarter partials merged via LDS scratch.
__global__ __launch_bounds__(512, 4) void attn_kernel(
    const short* __restrict__ Q, const short* __restrict__ K,
    const short* __restrict__ Vt, short* __restrict__ X)
{
    // [buf][ K 128x64 | V0 64x64 | V1 64x64 ] = 32 KB/buf, 64 KB total
    __shared__ __align__(16) short S[2][16384];

    const int wave = threadIdx.x >> 6, lane = threadIdx.x & 63;
    const int rc = lane & 15, quad = lane >> 4;
    const int qh = wave & 1, kh = wave >> 1;        // kh in 0..3
    const int L = blockIdx.x;                       // bijective XCD swizzle
    const int bh = (L & 7) * 2 + ((L >> 3) >> 5);   // xcd -> {2x, 2x+1}
    const int qb = (L >> 3) & 31;
    const size_t baseQK = (size_t)(bh >> 3) * SEQ * DM + (size_t)(bh & 7) * 64;
    const short* Qb = Q + baseQK;
    const short* Kb = K + baseQK;
    const short* Vb = Vt + (size_t)bh * 64 * SEQ;
    const int q0 = qb * 64 + qh * 32;               // wave's 32-query base

    short8 qa[2][2];
    #pragma unroll
    for (int ms = 0; ms < 2; ms++)
        #pragma unroll
        for (int h = 0; h < 2; h++)
            qa[ms][h] = *(const short8*)(Qb + (size_t)(q0 + ms * 16 + rc) * DM + h * 32 + quad * 8);

    short8 ones;
    #pragma unroll
    for (int j = 0; j < 8; j++) ones[j] = (short)0x3F80;   // bf16 1.0

    f32x4 o[4][2] = {};     // O^T partial (this key-quarter)
    f32x4 lsum[2] = {};     // partial l, all regs equal

    int koff[2][2], voff[4];
    #pragma unroll
    for (int kt = 0; kt < 2; kt++) {
        const int row = kh * 32 + rc * 2 + kt;     // K tile row (SH=1 swizzle)
        #pragma unroll
        for (int h = 0; h < 2; h++)
            koff[kt][h] = row * 64 + (((quad + 4 * h) ^ ((row >> 1) & 7)) * 8);
    }
    #pragma unroll
    for (int dt = 0; dt < 4; dt++) {
        const int row = dt * 16 + rc;
        voff[dt] = row * 64 + ((((kh & 1) * 4 + quad) ^ (row & 7)) * 8);
    }

    stage_tile<128, 8, 1>(Kb, DM, &S[0][0], wave, lane);
    stage_tile<64, 8>(Vb, SEQ, &S[0][8192], wave, lane);
    stage_tile<64, 8>(Vb + 64, SEQ, &S[0][12288], wave, lane);
    __syncthreads();

    for (int it = 0; it < 16; ++it) {
        const int cur = it & 1;
        if (it + 1 < 16) {
            const int k0n = (it + 1) * 128;
            stage_tile<128, 8, 1>(Kb + (size_t)k0n * DM, DM, &S[cur ^ 1][0], wave, lane);
            stage_tile<64, 8>(Vb + k0n, SEQ, &S[cur ^ 1][8192], wave, lane);
            stage_tile<64, 8>(Vb + k0n + 64, SEQ, &S[cur ^ 1][12288], wave, lane);
        }

        const short* Kt = &S[cur][0];
        const short* Vl = &S[cur][8192 + (kh >> 1) * 4096];

        short8 kf[2][2];
        #pragma unroll
        for (int kt = 0; kt < 2; kt++)
            #pragma unroll
            for (int h = 0; h < 2; h++)
                kf[kt][h] = *(const short8*)&Kt[koff[kt][h]];
        f32x4 s[2][2];
        __builtin_amdgcn_s_setprio(1);
        #pragma unroll
        for (int ms = 0; ms < 2; ms++)
            #pragma unroll
            for (int kt = 0; kt < 2; kt++) {
                f32x4 t = {};
                t = MFMA(kf[kt][0], qa[ms][0], t);
                t = MFMA(kf[kt][1], qa[ms][1], t);
                s[ms][kt] = t;
            }
        __builtin_amdgcn_s_setprio(0);
        short8 pa[2];
        #pragma unroll
        for (int ms = 0; ms < 2; ms++) {
            uint4v w;
            #pragma unroll
            for (int r = 0; r < 4; r++)
                w[r] = pack_bf16(EXP2(s[ms][0][r]), EXP2(s[ms][1][r]));
            pa[ms] = __builtin_bit_cast(short8, w);
        }
        __builtin_amdgcn_s_setprio(1);
        #pragma unroll
        for (int ms = 0; ms < 2; ms++)
            lsum[ms] = MFMA(ones, pa[ms], lsum[ms]);
        #pragma unroll
        for (int dt = 0; dt < 4; dt++) {
            short8 v = *(const short8*)&Vl[voff[dt]];
            #pragma unroll
            for (int ms = 0; ms < 2; ms++)
                o[dt][ms] = MFMA(v, pa[ms], o[dt][ms]);
        }
        __builtin_amdgcn_s_setprio(0);
        __syncthreads();
    }

    float* OM = (float*)&S[0][0];
    float* LM = OM + 12288;
    if (kh > 0) {
        #pragma unroll
        for (int dt = 0; dt < 4; dt++)
            #pragma unroll
            for (int ms = 0; ms < 2; ms++) {
                const int e = (kh - 1) * 16 + (dt * 2 + ms) * 2 + qh;
                *(f32x4*)&OM[(e * 64 + lane) * 4] = o[dt][ms];
            }
        #pragma unroll
        for (int ms = 0; ms < 2; ms++)
            LM[((kh - 1) * 4 + qh * 2 + ms) * 64 + lane] = lsum[ms][0];
    }
    __syncthreads();
    if (kh == 0) {
        short* Xr = X + baseQK;
        #pragma unroll
        for (int ms = 0; ms < 2; ms++) {
            float l = lsum[ms][0];
            #pragma unroll
            for (int p = 0; p < 3; p++) l += LM[(p * 4 + qh * 2 + ms) * 64 + lane];
            const float inv = 1.0f / l;
            const size_t rowoff = (size_t)(q0 + ms * 16 + rc) * DM;
            #pragma unroll
            for (int dt = 0; dt < 4; dt++) {
                f32x4 acc = o[dt][ms];
                #pragma unroll
                for (int p = 0; p < 3; p++) {
                    const int e = p * 16 + (dt * 2 + ms) * 2 + qh;
                    const f32x4 op = *(const f32x4*)&OM[(e * 64 + lane) * 4];
                    #pragma unroll
                    for (int r = 0; r < 4; r++) acc[r] += op[r];
                }
                short4v pk;
                #pragma unroll
                for (int r = 0; r < 4; r++) pk[r] = f2bf_r(acc[r] * inv);
                *(short4v*)(Xr + rowoff + dt * 16 + quad * 4) = pk;
            }
        }
    }
}

// ---------------------------------------------------------------------------
extern "C" void kernel_launch(void* const* d_in, const int* in_sizes, int n_in,
                              void* d_out, int out_size, void* d_ws, size_t ws_size,
                              hipStream_t stream) {
    // setup_inputs order: q, v, k, w_q, b_q, w_k, b_k, w_v, b_v, w_o, b_o
    char* ws = (char*)d_ws;
    const size_t SEQB = (size_t)NROW * DM * sizeof(short);  // 4 MB
    const size_t WB   = (size_t)DM * DM * sizeof(short);    // 512 KB
    const size_t BB   = (size_t)DM * sizeof(short);         // 1 KB

    size_t off = 0;
    short* wq = (short*)(ws + off); off += WB;
    short* wk = (short*)(ws + off); off += WB;
    short* wv = (short*)(ws + off); off += WB;
    short* wo = (short*)(ws + off); off += WB;
    short* bq = (short*)(ws + off); off += BB;
    short* bk = (short*)(ws + off); off += BB;
    short* bv = (short*)(ws + off); off += BB;
    short* bo = (short*)(ws + off); off += BB;
    off = (off + 255) & ~(size_t)255;
    short* Qp  = (short*)(ws + off); off += SEQB;
    short* Kp  = (short*)(ws + off); off += SEQB;
    short* Vtp = (short*)(ws + off); off += SEQB;
    short* Xp  = (short*)(ws + off); off += SEQB;
    int*   dtf = (int*)(ws + off);  off += 256;

    ConvArgs ca;
    ca.detect_src = d_in[0];
    const void* srcs[8] = {d_in[3], d_in[5], d_in[7], d_in[9],
                           d_in[4], d_in[6], d_in[8], d_in[10]};
    short* dsts[8] = {wq, wk, wv, wo, bq, bk, bv, bo};
    int ns[8] = {DM * DM, DM * DM, DM * DM, DM * DM, DM, DM, DM, DM};
    for (int i = 0; i < 8; i++) { ca.src[i] = srcs[i]; ca.dst[i] = dsts[i]; ca.n[i] = ns[i]; }
    ca.flag = dtf;
    convert_all<<<256, 256, 0, stream>>>(ca);

    QKVArgs qa;
    qa.Araw[0] = d_in[0];   // q
    qa.Araw[1] = d_in[2];   // k
    qa.Araw[2] = d_in[1];   // v
    qa.W[0] = wq; qa.W[1] = wk; qa.W[2] = wv;
    qa.Bi[0] = bq; qa.Bi[1] = bk; qa.Bi[2] = bv;
    qa.Cq = Qp; qa.Ck = Kp; qa.Cv = Vtp;
    qa.flag = dtf;
    qkv_gemm<<<dim3(NROW / 128, DM / 128, 3), 256, 0, stream>>>(qa);  // 384 blocks

    attn_kernel<<<dim3(512), 512, 0, stream>>>(Qp, Kp, Vtp, Xp);      // 512 blocks x 8 waves

    out_gemm<<<dim3(NROW / 64, DM / 64), 256, 0, stream>>>(
        Xp, wo, bo, d_out, dtf);                                       // 512 blocks
}

// Round 11
// 137.321 us; speedup vs baseline: 1.0551x; 1.0551x over previous
//
#include <hip/hip_runtime.h>
#include <hip/hip_bf16.h>

// MHA block: B=2, S=2048, D_MODEL=512, H=8, D_K=64.
// convert(+detect, writes dtype flag; 16B/lane vectorized both paths) ->
// fused QKV GEMM (128x128 tiles; Q pre-scaled 0.125*log2e; K natural order;
// V transposed [bh][d][s]) -> flash attention (512 blocks x 512 THREADS =
// 8 waves: (q-half) x (key-quarter); 16 waves/CU = 4 waves/SIMD; 128 keys/
// iter, ONE full __syncthreads per iter; swapped QK^T s=mfma(K,Q) with 32
// keys/wave -> IDENTITY key<->V-slot mapping; P packed in-register; FIXED-max
// exp2 softmax; O^T = mfma(Vt,P); 4 key-quarter partials merged via LDS
// scratch) -> output GEMM (64x64, dtype flag).   [r9 verified structure]

typedef __attribute__((ext_vector_type(8))) short short8;   // 8 bf16 (4 VGPRs)
typedef __attribute__((ext_vector_type(4))) short short4v;  // 4 bf16 (8B)
typedef __attribute__((ext_vector_type(4))) float f32x4;    // MFMA 16x16 accum
typedef __attribute__((ext_vector_type(4))) unsigned int uint4v;

#define DM 512
#define SEQ 2048
#define NROW 4096   // B * SEQ
#define LOG2E 1.44269504088896341f
#define MFMA(a, b, c) __builtin_amdgcn_mfma_f32_16x16x32_bf16(a, b, c, 0, 0, 0)
#define FENCE() __asm__ __volatile__("" ::: "memory")

#if __has_builtin(__builtin_amdgcn_exp2f)
#define EXP2(x) __builtin_amdgcn_exp2f(x)
#else
#define EXP2(x) exp2f(x)
#endif

__device__ __forceinline__ float bf_bits2f(short s) {
    unsigned int u = ((unsigned int)(unsigned short)s) << 16;
    return __builtin_bit_cast(float, u);
}
__device__ __forceinline__ short f2bf_r(float f) {   // round-half-up, 2 VALU
    unsigned int u = __builtin_bit_cast(unsigned int, f) + 0x8000u;
    return (short)(u >> 16);
}
__device__ __forceinline__ unsigned int pack_bf16(float lo, float hi) {
    unsigned int ul = __builtin_bit_cast(unsigned int, lo) + 0x8000u;
    unsigned int uh = __builtin_bit_cast(unsigned int, hi) + 0x8000u;
    return __builtin_amdgcn_perm(uh, ul, 0x07060302u);
}

__device__ __forceinline__ void gload_lds16(const void* src, void* lds_dst) {
    __builtin_amdgcn_global_load_lds(
        (const __attribute__((address_space(1))) unsigned int*)src,
        (__attribute__((address_space(3))) unsigned int*)lds_dst, 16, 0, 0);
}

// Stage ROWSx64 bf16 tile into LDS; granule swizzle swz(row) = (row>>SH)&7:
// LDS[row][b] = global[row][b ^ swz(row)] (16B blocks). Read accessor for
// global [row][cb*8+j]: lds[row*64 + ((cb ^ swz(row))*8) + j].
template <int ROWS, int NW, int SH = 0>
__device__ __forceinline__ void stage_tile(const short* __restrict__ gsrc, size_t gstride,
                                           short* lds, int wave, int lane) {
    constexpr int ISSUES = ROWS * 8 / (64 * NW);
    #pragma unroll
    for (int i = 0; i < ISSUES; i++) {
        const int blk = i * NW + wave;
        const int g = blk * 64 + lane;
        const int row = g >> 3;
        const int cb = (g & 7) ^ ((row >> SH) & 7);
        gload_lds16(gsrc + (size_t)row * gstride + cb * 8, lds + (size_t)blk * 512);
    }
}

// Dtype vote over first 1024 words of q. true = f32 inputs.
__device__ __forceinline__ bool detect_f32(const unsigned int* __restrict__ q, int* cnt_lds) {
    if (threadIdx.x == 0) *cnt_lds = 0;
    __syncthreads();
    int local = 0;
    for (int i = threadIdx.x; i < 1024; i += blockDim.x) {
        unsigned int lo = q[i] & 0x7FFFu;
        if (lo >= 0x3000u && lo < 0x4400u) local++;
    }
    if (local) atomicAdd(cnt_lds, local);
    __syncthreads();
    return *cnt_lds < 512;
}

// ---------------------------------------------------------------------------
// Convert all 11 tensors, 16B/lane stores (G13 sweet spot): f32 path reads
// 32B + writes 16B per lane-iter; bf16 passthrough copies 16B per lane-iter.
struct ConvArgs { const void* src[11]; short* dst[11]; int n[11]; int* flag; };
__global__ void convert_all(ConvArgs a) {
    __shared__ int cnt;
    const bool f32m = detect_f32((const unsigned int*)a.src[0], &cnt);
    if (threadIdx.x == 0) *a.flag = f32m ? 1 : 0;   // all blocks write same value
    const int tid = blockIdx.x * 256 + threadIdx.x;
    const int stride = gridDim.x * 256;
    if (f32m) {
        for (int s = 0; s < 11; s++) {
            const float4* sp = (const float4*)a.src[s];
            uint4v* dp = (uint4v*)a.dst[s];
            const int n8 = a.n[s] >> 3;             // all n divisible by 8
            for (int i = tid; i < n8; i += stride) {
                const float4 x = sp[2 * i];
                const float4 y = sp[2 * i + 1];
                uint4v w;
                w[0] = pack_bf16(x.x, x.y); w[1] = pack_bf16(x.z, x.w);
                w[2] = pack_bf16(y.x, y.y); w[3] = pack_bf16(y.z, y.w);
                dp[i] = w;
            }
        }
    } else {
        for (int s = 0; s < 11; s++) {
            const uint4v* sp = (const uint4v*)a.src[s];
            uint4v* dp = (uint4v*)a.dst[s];
            const int n8 = a.n[s] >> 3;
            for (int i = tid; i < n8; i += stride) dp[i] = sp[i];
        }
    }
}

// ---------------------------------------------------------------------------
// Double-buffered GEMM core: MT(M) x NT(N) tile, BK=64, 4 waves (wave owns
// MT/4 rows x NT cols). Stage k+1 while computing k; vmcnt(INFLIGHT) keeps
// prefetch in flight (no per-iter drain). Verified protocol.
template <int MT, int NT>
__device__ __forceinline__ void gemm_core(const short* __restrict__ A,
                                          const short* __restrict__ W,
                                          int m0, int n0, short* Alds, short* Blds,
                                          int wave, int lane,
                                          f32x4 (&acc)[MT / 64][NT / 16]) {
    const int rc = lane & 15, quad = lane >> 4;
    const short* Ag = A + (size_t)m0 * DM;
    const short* Bg = W + (size_t)n0 * DM;
    constexpr int ABUF = MT * 64, BBUF = NT * 64;
    constexpr int INFLIGHT = (MT + NT) * 8 / 256;   // per-wave glds instrs per stage
    constexpr int NITER = DM / 64;

    stage_tile<MT, 4>(Ag, DM, Alds, wave, lane);
    stage_tile<NT, 4>(Bg, DM, Blds, wave, lane);

    for (int i = 0; i < NITER; i++) {
        const int cur = i & 1;
        const short* Ac = Alds + cur * ABUF;
        const short* Bc = Blds + cur * BBUF;
        if (i + 1 < NITER) {   // overwrite of buf[cur^1] is safe: barrier at loop end
            stage_tile<MT, 4>(Ag + (i + 1) * 64, DM, Alds + (cur ^ 1) * ABUF, wave, lane);
            stage_tile<NT, 4>(Bg + (i + 1) * 64, DM, Blds + (cur ^ 1) * BBUF, wave, lane);
            __builtin_amdgcn_s_waitcnt(0x3F70 | INFLIGHT);   // cur's loads done
        } else {
            __builtin_amdgcn_s_waitcnt(0x3F70);              // vmcnt(0)
        }
        FENCE();
        __builtin_amdgcn_s_barrier();   // cur visible to all waves
        FENCE();
        #pragma unroll
        for (int h = 0; h < 2; h++) {
            short8 bf[NT / 16];
            #pragma unroll
            for (int nt = 0; nt < NT / 16; nt++) {
                const int br = nt * 16 + rc;
                bf[nt] = *(const short8*)&Bc[br * 64 + (((quad + 4 * h) ^ (br & 7)) * 8)];
            }
            #pragma unroll
            for (int ms = 0; ms < MT / 64; ms++) {
                const int ar = wave * (MT / 4) + ms * 16 + rc;
                short8 af = *(const short8*)&Ac[ar * 64 + (((quad + 4 * h) ^ (ar & 7)) * 8)];
                #pragma unroll
                for (int nt = 0; nt < NT / 16; nt++)
                    acc[ms][nt] = MFMA(af, bf[nt], acc[ms][nt]);
            }
        }
        FENCE();
        __builtin_amdgcn_s_barrier();   // all waves done reading cur
        FENCE();
    }
}

// Fused QKV projection, 128x128 tiles. z=0: Q scaled by 0.125*log2e. z=1: K
// (natural order). z=2: V transposed Vt[((b*8+h)*64+d)*SEQ + s].
struct QKVArgs {
    const short* A[3]; const short* W[3]; const short* Bi[3];
    short* Cq; short* Ck; short* Cv;
};
__global__ __launch_bounds__(256, 2) void qkv_gemm(QKVArgs args) {
    __shared__ __align__(16) short Alds[2][128 * 64];   // 32 KB
    __shared__ __align__(16) short Blds[2][128 * 64];   // 32 KB
    const int z = blockIdx.z;
    const int wave = threadIdx.x >> 6, lane = threadIdx.x & 63;
    const int rc = lane & 15, quad = lane >> 4;
    const int m0 = blockIdx.x * 128, n0 = blockIdx.y * 128;

    f32x4 acc[2][8] = {};
    gemm_core<128, 128>(args.A[z], args.W[z], m0, n0, &Alds[0][0], &Blds[0][0], wave, lane, acc);
    const short* bias = args.Bi[z];

    if (z == 2) {
        #pragma unroll
        for (int ms = 0; ms < 2; ms++) {
            const int mw = m0 + wave * 32 + ms * 16;
            const int b = mw >> 11, sb = (mw & 2047) + quad * 4;
            #pragma unroll
            for (int nt = 0; nt < 8; nt++) {
                const int dg = n0 + nt * 16 + rc;       // global output col = head dim
                const int hh = dg >> 6, dd = dg & 63;
                const float bv = bf_bits2f(bias[dg]);
                short4v pk;
                #pragma unroll
                for (int r = 0; r < 4; r++) pk[r] = f2bf_r(acc[ms][nt][r] + bv);
                *(short4v*)(args.Cv + ((size_t)((b * 8 + hh) * 64 + dd)) * SEQ + sb) = pk;
            }
        }
    } else {
        short* C = (z == 0) ? args.Cq : args.Ck;
        const float sc = (z == 0) ? (0.125f * LOG2E) : 1.0f;
        #pragma unroll
        for (int ms = 0; ms < 2; ms++) {
            const int mw = m0 + wave * 32 + ms * 16;
            #pragma unroll
            for (int nt = 0; nt < 8; nt++) {
                const int col = n0 + nt * 16 + rc;
                const float bv = bf_bits2f(bias[col]);
                #pragma unroll
                for (int r = 0; r < 4; r++)
                    C[(size_t)(mw + quad * 4 + r) * DM + col] = f2bf_r((acc[ms][nt][r] + bv) * sc);
            }
        }
    }
}

// Output projection (64x64 -> 512 blocks); f32/bf16 store per dtype flag.
__global__ __launch_bounds__(256, 4) void out_gemm(
    const short* __restrict__ A, const short* __restrict__ W,
    const short* __restrict__ bias, void* __restrict__ Cout,
    const int* __restrict__ dtf) {
    __shared__ __align__(16) short Alds[2][64 * 64];
    __shared__ __align__(16) short Blds[2][64 * 64];
    const bool f32out = (*dtf != 0);
    const int wave = threadIdx.x >> 6, lane = threadIdx.x & 63;
    const int rc = lane & 15, quad = lane >> 4;
    const int m0 = blockIdx.x * 64, n0 = blockIdx.y * 64;
    f32x4 acc[1][4] = {};
    gemm_core<64, 64>(A, W, m0, n0, &Alds[0][0], &Blds[0][0], wave, lane, acc);
    const int mw = m0 + wave * 16;
    #pragma unroll
    for (int nt = 0; nt < 4; nt++) {
        const int col = n0 + nt * 16 + rc;
        const float bv = bf_bits2f(bias[col]);
        #pragma unroll
        for (int r = 0; r < 4; r++) {
            const size_t idx = (size_t)(mw + quad * 4 + r) * DM + col;
            const float val = acc[0][nt][r] + bv;
            if (f32out) ((float*)Cout)[idx] = val;
            else        ((short*)Cout)[idx] = f2bf_r(val);
        }
    }
}

// ---------------------------------------------------------------------------
// Flash attention (r9 verified, byte-identical): block = 64 queries x 2048
// keys for one (b,h), 512 threads, 8 waves: qh = wave&1 (32q, ms=2),
// kh = wave>>1 (key-quarter: 32 of the 128 keys/iter). 16 iters, double-
// buffered, ONE full-drain __syncthreads per iteration. 2 blocks/CU x 8
// waves = 4 waves/SIMD. Swapped QK^T identity-slotted; in-register P;
// fixed-max exp2 softmax; O^T = mfma(Vt,P); LDS merge of 4 key-quarters.
__global__ __launch_bounds__(512, 4) void attn_kernel(
    const short* __restrict__ Q, const short* __restrict__ K,
    const short* __restrict__ Vt, short* __restrict__ X)
{
    // [buf][ K 128x64 | V0 64x64 | V1 64x64 ] = 32 KB/buf, 64 KB total
    __shared__ __align__(16) short S[2][16384];

    const int wave = threadIdx.x >> 6, lane = threadIdx.x & 63;
    const int rc = lane & 15, quad = lane >> 4;
    const int qh = wave & 1, kh = wave >> 1;        // kh in 0..3
    const int L = blockIdx.x;                       // bijective XCD swizzle
    const int bh = (L & 7) * 2 + ((L >> 3) >> 5);   // xcd -> {2x, 2x+1}
    const int qb = (L >> 3) & 31;
    const size_t baseQK = (size_t)(bh >> 3) * SEQ * DM + (size_t)(bh & 7) * 64;
    const short* Qb = Q + baseQK;
    const short* Kb = K + baseQK;
    const short* Vb = Vt + (size_t)bh * 64 * SEQ;
    const int q0 = qb * 64 + qh * 32;               // wave's 32-query base

    short8 qa[2][2];
    #pragma unroll
    for (int ms = 0; ms < 2; ms++)
        #pragma unroll
        for (int h = 0; h < 2; h++)
            qa[ms][h] = *(const short8*)(Qb + (size_t)(q0 + ms * 16 + rc) * DM + h * 32 + quad * 8);

    short8 ones;
    #pragma unroll
    for (int j = 0; j < 8; j++) ones[j] = (short)0x3F80;   // bf16 1.0

    f32x4 o[4][2] = {};     // O^T partial (this key-quarter): o[dt][ms][r] =
                            //   O[d=dt*16+quad*4+r][q=q0+ms*16+rc]
    f32x4 lsum[2] = {};     // partial l, all regs equal: l[q=q0+ms*16+rc]

    // loop-invariant LDS frag offsets (shorts)
    int koff[2][2], voff[4];
    #pragma unroll
    for (int kt = 0; kt < 2; kt++) {
        const int row = kh * 32 + rc * 2 + kt;     // K tile row (SH=1 swizzle)
        #pragma unroll
        for (int h = 0; h < 2; h++)
            koff[kt][h] = row * 64 + (((quad + 4 * h) ^ ((row >> 1) & 7)) * 8);
    }
    #pragma unroll
    for (int dt = 0; dt < 4; dt++) {
        const int row = dt * 16 + rc;              // V sub-tile (kh>>1), col block (kh&1)*4+quad
        voff[dt] = row * 64 + ((((kh & 1) * 4 + quad) ^ (row & 7)) * 8);
    }

    // stage tile 0, full drain before first compute
    stage_tile<128, 8, 1>(Kb, DM, &S[0][0], wave, lane);
    stage_tile<64, 8>(Vb, SEQ, &S[0][8192], wave, lane);
    stage_tile<64, 8>(Vb + 64, SEQ, &S[0][12288], wave, lane);
    __syncthreads();

    for (int it = 0; it < 16; ++it) {
        const int cur = it & 1;
        // issue next-tile prefetch (completes under this tile's compute;
        // buf[cur^1] readers finished at the previous __syncthreads)
        if (it + 1 < 16) {
            const int k0n = (it + 1) * 128;
            stage_tile<128, 8, 1>(Kb + (size_t)k0n * DM, DM, &S[cur ^ 1][0], wave, lane);
            stage_tile<64, 8>(Vb + k0n, SEQ, &S[cur ^ 1][8192], wave, lane);
            stage_tile<64, 8>(Vb + k0n + 64, SEQ, &S[cur ^ 1][12288], wave, lane);
        }

        const short* Kt = &S[cur][0];
        const short* Vl = &S[cur][8192 + (kh >> 1) * 4096];

        // K fragments (A-operand of swapped QK^T)
        short8 kf[2][2];
        #pragma unroll
        for (int kt = 0; kt < 2; kt++)
            #pragma unroll
            for (int h = 0; h < 2; h++)
                kf[kt][h] = *(const short8*)&Kt[koff[kt][h]];
        // swapped QK^T: s[ms][kt] cols = q, rows = keys (identity-slotted)
        f32x4 s[2][2];
        __builtin_amdgcn_s_setprio(1);
        #pragma unroll
        for (int ms = 0; ms < 2; ms++)
            #pragma unroll
            for (int kt = 0; kt < 2; kt++) {
                f32x4 t = {};
                t = MFMA(kf[kt][0], qa[ms][0], t);
                t = MFMA(kf[kt][1], qa[ms][1], t);
                s[ms][kt] = t;
            }
        __builtin_amdgcn_s_setprio(0);
        // fixed-max softmax: P = exp2(s), packed in-register into PV fragment.
        // elem j = 2r+kt  ->  word w: (s[0][w], s[1][w])
        short8 pa[2];
        #pragma unroll
        for (int ms = 0; ms < 2; ms++) {
            uint4v w;
            #pragma unroll
            for (int r = 0; r < 4; r++)
                w[r] = pack_bf16(EXP2(s[ms][0][r]), EXP2(s[ms][1][r]));
            pa[ms] = __builtin_bit_cast(short8, w);
        }
        __builtin_amdgcn_s_setprio(1);
        #pragma unroll
        for (int ms = 0; ms < 2; ms++)
            lsum[ms] = MFMA(ones, pa[ms], lsum[ms]);
        #pragma unroll
        for (int dt = 0; dt < 4; dt++) {
            short8 v = *(const short8*)&Vl[voff[dt]];
            #pragma unroll
            for (int ms = 0; ms < 2; ms++)
                o[dt][ms] = MFMA(v, pa[ms], o[dt][ms]);   // A=Vt rows d, B=P^T -> O^T
        }
        __builtin_amdgcn_s_setprio(0);
        // single full-drain barrier: prefetch(it+1) landed, all waves done
        // reading buf[cur] -> both buffers safe for next iteration
        __syncthreads();
    }

    // merge 4 key-quarters via LDS scratch over dead K/V buffers (51 KB used
    // of 64 KB), full syncs on both sides. kh>0 publish; kh==0 combine+store.
    float* OM = (float*)&S[0][0];        // 48 entries x 64 lanes x f32x4 = 48 KB
    float* LM = OM + 12288;              // 12 x 64 f32 = 3 KB
    if (kh > 0) {
        #pragma unroll
        for (int dt = 0; dt < 4; dt++)
            #pragma unroll
            for (int ms = 0; ms < 2; ms++) {
                const int e = (kh - 1) * 16 + (dt * 2 + ms) * 2 + qh;
                *(f32x4*)&OM[(e * 64 + lane) * 4] = o[dt][ms];
            }
        #pragma unroll
        for (int ms = 0; ms < 2; ms++)
            LM[((kh - 1) * 4 + qh * 2 + ms) * 64 + lane] = lsum[ms][0];
    }
    __syncthreads();
    if (kh == 0) {
        short* Xr = X + baseQK;
        #pragma unroll
        for (int ms = 0; ms < 2; ms++) {
            float l = lsum[ms][0];
            #pragma unroll
            for (int p = 0; p < 3; p++) l += LM[(p * 4 + qh * 2 + ms) * 64 + lane];
            const float inv = 1.0f / l;
            const size_t rowoff = (size_t)(q0 + ms * 16 + rc) * DM;
            #pragma unroll
            for (int dt = 0; dt < 4; dt++) {
                f32x4 acc = o[dt][ms];
                #pragma unroll
                for (int p = 0; p < 3; p++) {
                    const int e = p * 16 + (dt * 2 + ms) * 2 + qh;
                    const f32x4 op = *(const f32x4*)&OM[(e * 64 + lane) * 4];
                    #pragma unroll
                    for (int r = 0; r < 4; r++) acc[r] += op[r];
                }
                short4v pk;
                #pragma unroll
                for (int r = 0; r < 4; r++) pk[r] = f2bf_r(acc[r] * inv);
                *(short4v*)(Xr + rowoff + dt * 16 + quad * 4) = pk;
            }
        }
    }
}

// ---------------------------------------------------------------------------
extern "C" void kernel_launch(void* const* d_in, const int* in_sizes, int n_in,
                              void* d_out, int out_size, void* d_ws, size_t ws_size,
                              hipStream_t stream) {
    // setup_inputs order: q, v, k, w_q, b_q, w_k, b_k, w_v, b_v, w_o, b_o
    char* ws = (char*)d_ws;
    const size_t SEQB = (size_t)NROW * DM * sizeof(short);  // 4 MB
    const size_t WB   = (size_t)DM * DM * sizeof(short);    // 512 KB
    const size_t BB   = (size_t)DM * sizeof(short);         // 1 KB

    size_t off = 0;
    short* qc = (short*)(ws + off); off += SEQB;
    short* vc = (short*)(ws + off); off += SEQB;
    short* kc = (short*)(ws + off); off += SEQB;
    short* wq = (short*)(ws + off); off += WB;
    short* wk = (short*)(ws + off); off += WB;
    short* wv = (short*)(ws + off); off += WB;
    short* wo = (short*)(ws + off); off += WB;
    short* bq = (short*)(ws + off); off += BB;
    short* bk = (short*)(ws + off); off += BB;
    short* bv = (short*)(ws + off); off += BB;
    short* bo = (short*)(ws + off); off += BB;
    off = (off + 255) & ~(size_t)255;
    short* Qp  = (short*)(ws + off); off += SEQB;
    short* Kp  = (short*)(ws + off); off += SEQB;
    short* Vtp = (short*)(ws + off); off += SEQB;
    short* Xp  = (short*)(ws + off); off += SEQB;
    int*   dtf = (int*)(ws + off);  off += 256;

    ConvArgs ca;
    const void* srcs[11] = {d_in[0], d_in[1], d_in[2], d_in[3], d_in[5], d_in[7],
                            d_in[9], d_in[4], d_in[6], d_in[8], d_in[10]};
    short* dsts[11] = {qc, vc, kc, wq, wk, wv, wo, bq, bk, bv, bo};
    int ns[11] = {NROW * DM, NROW * DM, NROW * DM, DM * DM, DM * DM, DM * DM,
                  DM * DM, DM, DM, DM, DM};
    for (int i = 0; i < 11; i++) { ca.src[i] = srcs[i]; ca.dst[i] = dsts[i]; ca.n[i] = ns[i]; }
    ca.flag = dtf;
    convert_all<<<1024, 256, 0, stream>>>(ca);

    QKVArgs qa;
    qa.A[0] = qc; qa.A[1] = kc; qa.A[2] = vc;
    qa.W[0] = wq; qa.W[1] = wk; qa.W[2] = wv;
    qa.Bi[0] = bq; qa.Bi[1] = bk; qa.Bi[2] = bv;
    qa.Cq = Qp; qa.Ck = Kp; qa.Cv = Vtp;
    qkv_gemm<<<dim3(NROW / 128, DM / 128, 3), 256, 0, stream>>>(qa);  // 384 blocks

    attn_kernel<<<dim3(512), 512, 0, stream>>>(Qp, Kp, Vtp, Xp);      // 512 blocks x 8 waves

    out_gemm<<<dim3(NROW / 64, DM / 64), 256, 0, stream>>>(
        Xp, wo, bo, d_out, dtf);                                       // 512 blocks
}